// Round 1
// baseline (98.971 us; speedup 1.0000x reference)
//
#include <hip/hip_runtime.h>
#include <math.h>

// MS_QCR: conv-short + conv-long feature nets -> 5-qubit statevector sim -> readout.
// One thread per batch row; 32 complex amplitudes held in registers.
// Uniform (weight-derived) tables built once per block into LDS:
//   - rx/ry half-angle cos/sin per (layer, qubit)            : 4*15 floats
//   - per-layer combined ZZ phase per basis state (cos,sin)  : 2*96 floats
//   - readout-weighted Z coefficient per basis state         : 32 floats

__global__ __launch_bounds__(256) void qcr_kernel(
    const float* __restrict__ x_short, const float* __restrict__ x_long,
    const float* __restrict__ conv_s_w, const float* __restrict__ conv_s_b,
    const float* __restrict__ lin_s_w,  const float* __restrict__ lin_s_b,
    const float* __restrict__ conv_l_w, const float* __restrict__ conv_l_b,
    const float* __restrict__ lin_l_w,  const float* __restrict__ lin_l_b,
    const float* __restrict__ rw,       const float* __restrict__ readout_w,
    const float* __restrict__ readout_b, float* __restrict__ out, int nb)
{
    __shared__ float s_rxc[15], s_rxs[15], s_ryc[15], s_rys[15];
    __shared__ float s_zzc[96], s_zzs[96], s_coef[32];

    const int tid = threadIdx.x;

    // ---- build uniform tables (weight-only; same for every block) ----
    if (tid < 15) {
        const int l = tid / 5, i = tid % 5;
        const float tx = rw[l*25 + i*5 + 0] * 0.5f;
        const float ty = rw[l*25 + i*5 + 1] * 0.5f;
        s_rxc[tid] = cosf(tx); s_rxs[tid] = sinf(tx);
        s_ryc[tid] = cosf(ty); s_rys[tid] = sinf(ty);
    }
    if (tid >= 32 && tid < 128) {
        const int e = tid - 32;
        const int l = e >> 5, bi = e & 31;
        float ang = 0.f;
        for (int i = 0; i < 5; ++i) {
            const float si = ((bi >> (4 - i)) & 1) ? -1.f : 1.f;
            for (int j = i + 1; j < 5; ++j) {
                const float sj = ((bi >> (4 - j)) & 1) ? -1.f : 1.f;
                ang += rw[l*25 + i*5 + j] * si * sj;
            }
        }
        ang *= -0.5f;
        s_zzc[e] = cosf(ang); s_zzs[e] = sinf(ang);
    }
    if (tid >= 128 && tid < 160) {
        const int bi = tid - 128;
        float c = 0.f;
        for (int w = 0; w < 5; ++w) {
            const float sw = ((bi >> (4 - w)) & 1) ? -1.f : 1.f;
            c += readout_w[w] * sw;
        }
        s_coef[bi] = c;
    }
    __syncthreads();

    const int b = blockIdx.x * 256 + tid;
    if (b >= nb) return;

    // ---------------- classical: short branch ----------------
    float xs[5];
    #pragma unroll
    for (int p = 0; p < 5; ++p) xs[p] = x_short[b*5 + p];

    float f0 = lin_s_b[0], f1 = lin_s_b[1];
    #pragma unroll
    for (int c = 0; c < 4; ++c) {
        #pragma unroll
        for (int p = 0; p < 5; ++p) {
            float h = conv_s_b[c];
            #pragma unroll
            for (int k = 0; k < 3; ++k) {
                const int q = p - 1 + k;             // pad (1,1)
                if (q >= 0 && q < 5) h += conv_s_w[c*3 + k] * xs[q];
            }
            h = fmaxf(h, 0.f);
            f0 += lin_s_w[      c*5 + p] * h;
            f1 += lin_s_w[20 + c*5 + p] * h;
        }
    }

    // ---------------- classical: long branch ----------------
    float xl[20];
    #pragma unroll
    for (int p = 0; p < 20; ++p) xl[p] = x_long[b*20 + p];

    float g0 = lin_l_b[0], g1 = lin_l_b[1];
    #pragma unroll
    for (int c = 0; c < 4; ++c) {
        #pragma unroll
        for (int q = 0; q < 10; ++q) {
            float hm = 0.f;                          // relu(max(a,b)) = max(max(a,b),0)
            #pragma unroll
            for (int t = 0; t < 2; ++t) {
                const int p = 2*q + t;
                float h = conv_l_b[c];
                #pragma unroll
                for (int k = 0; k < 5; ++k) {
                    const int u = p - 2 + k;         // pad (2,2)
                    if (u >= 0 && u < 20) h += conv_l_w[c*5 + k] * xl[u];
                }
                hm = fmaxf(hm, h);
            }
            g0 += lin_l_w[      c*10 + q] * hm;
            g1 += lin_l_w[40 + c*10 + q] * hm;
        }
    }

    // ---------------- quantum init: product state ----------------
    // angles = [f0, f1, 0, g0, g1]; RY(a)|0> = [cos(a/2), sin(a/2)] (real)
    float p0c, p0s, p1c, p1s, p3c, p3s, p4c, p4s;
    sincosf(f0 * 0.5f, &p0s, &p0c);
    sincosf(f1 * 0.5f, &p1s, &p1c);
    sincosf(g0 * 0.5f, &p3s, &p3c);
    sincosf(g1 * 0.5f, &p4s, &p4c);

    float ar[32], ai[32];
    #pragma unroll
    for (int idx = 0; idx < 32; ++idx) {
        float v;
        if ((idx >> 2) & 1) {
            v = 0.f;                                  // wire 2 angle = 0 -> sin = 0
        } else {
            v = ((idx >> 4) & 1 ? p0s : p0c)
              * ((idx >> 3) & 1 ? p1s : p1c)
              * ((idx >> 1) & 1 ? p3s : p3c)
              * ((idx      ) & 1 ? p4s : p4c);
        }
        ar[idx] = v; ai[idx] = 0.f;
    }

    // ---------------- 3 layers: (RX,RY) per qubit, then fused ZZ phases ----------------
    for (int l = 0; l < 3; ++l) {                     // runtime loop: keeps code size down
        #pragma unroll
        for (int qb = 0; qb < 5; ++qb) {
            const float rc = s_rxc[l*5 + qb], rs = s_rxs[l*5 + qb];
            const float yc = s_ryc[l*5 + qb], ys = s_rys[l*5 + qb];
            const int str = 1 << (4 - qb);
            #pragma unroll
            for (int g = 0; g < 16; ++g) {
                const int i0 = ((g & ~(str - 1)) << 1) | (g & (str - 1));
                const int i1 = i0 | str;
                const float a0r = ar[i0], a0i = ai[i0];
                const float a1r = ar[i1], a1i = ai[i1];
                // RX: [[c,-is],[-is,c]]
                const float n0r =  rc*a0r + rs*a1i;
                const float n0i =  rc*a0i - rs*a1r;
                const float n1r =  rs*a0i + rc*a1r;
                const float n1i = -rs*a0r + rc*a1i;
                // RY: [[c,-s],[s,c]]
                ar[i0] = yc*n0r - ys*n1r;
                ai[i0] = yc*n0i - ys*n1i;
                ar[i1] = ys*n0r + yc*n1r;
                ai[i1] = ys*n0i + yc*n1i;
            }
        }
        #pragma unroll
        for (int idx = 0; idx < 32; ++idx) {
            const float pc = s_zzc[l*32 + idx], ps = s_zzs[l*32 + idx];
            const float r = ar[idx]*pc - ai[idx]*ps;
            ai[idx]       = ar[idx]*ps + ai[idx]*pc;
            ar[idx]       = r;
        }
    }

    // ---------------- fused expectation + readout ----------------
    float acc = readout_b[0];
    #pragma unroll
    for (int idx = 0; idx < 32; ++idx)
        acc += (ar[idx]*ar[idx] + ai[idx]*ai[idx]) * s_coef[idx];
    out[b] = acc;
}

extern "C" void kernel_launch(void* const* d_in, const int* in_sizes, int n_in,
                              void* d_out, int out_size, void* d_ws, size_t ws_size,
                              hipStream_t stream) {
    const float* x_short    = (const float*)d_in[0];
    const float* x_long     = (const float*)d_in[1];
    const float* conv_s_w   = (const float*)d_in[2];
    const float* conv_s_b   = (const float*)d_in[3];
    const float* lin_s_w    = (const float*)d_in[4];
    const float* lin_s_b    = (const float*)d_in[5];
    const float* conv_l_w   = (const float*)d_in[6];
    const float* conv_l_b   = (const float*)d_in[7];
    const float* lin_l_w    = (const float*)d_in[8];
    const float* lin_l_b    = (const float*)d_in[9];
    const float* rw         = (const float*)d_in[10];
    const float* readout_w  = (const float*)d_in[11];
    const float* readout_b  = (const float*)d_in[12];
    float* out = (float*)d_out;

    const int nb = in_sizes[0] / 5;
    dim3 grid((nb + 255) / 256), block(256);
    hipLaunchKernelGGL(qcr_kernel, grid, block, 0, stream,
                       x_short, x_long, conv_s_w, conv_s_b, lin_s_w, lin_s_b,
                       conv_l_w, conv_l_b, lin_l_w, lin_l_b, rw, readout_w,
                       readout_b, out, nb);
}